// Round 11
// baseline (673.488 us; speedup 1.0000x reference)
//
#include <hip/hip_runtime.h>
#include <cstdint>

#define BQ 4
#define QPB 65536
#define QTOT (BQ*QPB)          /* 262144 */
#define TRIN 393216            /* 3*32*64*64 */
#define TRI_OUT (BQ*TRIN)      /* 1572864 */

typedef __attribute__((ext_vector_type(8))) __bf16 bf16x8;
typedef __attribute__((ext_vector_type(4))) float f32x4;

__device__ __forceinline__ unsigned short f2bf(float f) {
    unsigned u = __float_as_uint(f);
    u += 0x7fffu + ((u >> 16) & 1u);
    return (unsigned short)(u >> 16);
}
__device__ __forceinline__ float bflo(unsigned u) {
    return __uint_as_float(u << 16);
}
__device__ __forceinline__ float bfhi(unsigned u) {
    return __uint_as_float(u & 0xffff0000u);
}
__device__ __forceinline__ unsigned cvt_pk_bf16(float lo, float hi) {
    unsigned r;
    asm("v_cvt_pk_bf16_f32 %0, %1, %2" : "=v"(r) : "v"(lo), "v"(hi));
    return r;
}
__device__ __forceinline__ float fast_rcp(float d) {
    float r;
    asm("v_rcp_f32 %0, %1" : "=v"(r) : "v"(d));
    return r;
}
__device__ __forceinline__ float silu_f(float x) {
    return x * fast_rcp(1.0f + __expf(-x));
}
// stored position within a 64-col group -> true column (sigma^-1)
__device__ __forceinline__ int c_true(int p) {
    return (p & ~63) + ((p & 3) * 16 + ((p & 63) >> 2));
}

// ---------------- K0: pack MLP weights (fragment order + sigma K-permute) ----------------
__global__ __launch_bounds__(256) void k_prep_w(
    const float* __restrict__ mw0, const float* __restrict__ mw1, const float* __restrict__ mw2,
    const float* __restrict__ sdf_w, const float* __restrict__ occ_w,
    unsigned short* __restrict__ wt0, unsigned short* __restrict__ wt1,
    unsigned short* __restrict__ wt2, float* __restrict__ sdfp, float* __restrict__ occp)
{
    int idx = blockIdx.x * 256 + threadIdx.x;
    if (idx < 163840) {
        const float* src;
        unsigned short* dst;
        int rel;
        bool perm;
        int kmax;
        if (idx < 32768)       { rel = idx;         src = mw0; dst = wt0; perm = false; kmax = 99;  }
        else if (idx < 98304)  { rel = idx - 32768; src = mw1; dst = wt1; perm = true;  kmax = 256; }
        else                   { rel = idx - 98304; src = mw2; dst = wt2; perm = true;  kmax = 256; }
        int e  = rel & 7;
        int kg = (rel >> 3) & 3;
        int n  = (rel >> 5) & 255;
        int t  = rel >> 13;
        int ks = t * 32 + kg * 8 + e;          // stored k
        int k  = perm ? c_true(ks) : ks;       // source k
        float v = (ks < kmax) ? src[k * 256 + n] : 0.0f;
        dst[rel] = f2bf(v);
    } else if (idx < 164352) {
        int r = idx - 163840;
        int p = r & 255, which = r >> 8;
        float v = (which ? occ_w : sdf_w)[c_true(p)];
        (which ? occp : sdfp)[p] = v;
    }
}

// ---------------- K1: h = silu(z @ w1 + b1), [4][512] f32 ----------------
__global__ __launch_bounds__(256) void k_h(
    const float* __restrict__ z, const float* __restrict__ w1,
    const float* __restrict__ b1, float* __restrict__ hout)
{
    int gid = blockIdx.x * 256 + threadIdx.x;   // 2048 total
    int b = gid >> 9, n = gid & 511;
    float acc = b1[n];
    #pragma unroll 8
    for (int k = 0; k < 256; ++k)
        acc += z[b * 256 + k] * w1[k * 512 + n];
    hout[gid] = silu_f(acc);
}

// ---------------- K2: triplanes = h @ w2 + b2 (unchanged, near HBM floor) ----------------
__global__ __launch_bounds__(256) void k_triplane(
    const float* __restrict__ w2, const float* __restrict__ b2,
    const float* __restrict__ h, float* __restrict__ outTri,
    unsigned short* __restrict__ triT)
{
    __shared__ float hs[2048];
    int t = threadIdx.x;
    ((float4*)hs)[t]       = ((const float4*)h)[t];
    ((float4*)hs)[t + 256] = ((const float4*)h)[t + 256];
    __syncthreads();
    int g = blockIdx.x * 256 + t;            // 196608 threads
    int j = g * 2;
    const float* wj = w2 + j;
    float ax[4] = {0.f, 0.f, 0.f, 0.f}, ay[4] = {0.f, 0.f, 0.f, 0.f};

    for (int k0 = 0; k0 < 512; k0 += 8) {
        float2 wv[8];
        #pragma unroll
        for (int u = 0; u < 8; ++u)
            wv[u] = *(const float2*)(wj + (size_t)(k0 + u) * TRIN);
        float4 hv[4][2];
        #pragma unroll
        for (int b = 0; b < 4; ++b) {
            hv[b][0] = *(const float4*)&hs[b * 512 + k0];
            hv[b][1] = *(const float4*)&hs[b * 512 + k0 + 4];
        }
        #pragma unroll
        for (int b = 0; b < 4; ++b) {
            ax[b] += hv[b][0].x * wv[0].x + hv[b][0].y * wv[1].x
                   + hv[b][0].z * wv[2].x + hv[b][0].w * wv[3].x
                   + hv[b][1].x * wv[4].x + hv[b][1].y * wv[5].x
                   + hv[b][1].z * wv[6].x + hv[b][1].w * wv[7].x;
            ay[b] += hv[b][0].x * wv[0].y + hv[b][0].y * wv[1].y
                   + hv[b][0].z * wv[2].y + hv[b][0].w * wv[3].y
                   + hv[b][1].x * wv[4].y + hv[b][1].y * wv[5].y
                   + hv[b][1].z * wv[6].y + hv[b][1].w * wv[7].y;
        }
    }

    float2 bj = *(const float2*)(b2 + j);
    int x = j & 63, y = (j >> 6) & 63, c = (j >> 12) & 31, p = j >> 17;
    int ttb = ((p * 64 + y) * 64 + x) * 32 + c;
    #pragma unroll
    for (int b = 0; b < 4; ++b) {
        float vX = ax[b] + bj.x, vY = ay[b] + bj.y;
        float2 o; o.x = vX; o.y = vY;
        *(float2*)(outTri + (size_t)b * TRIN + j) = o;
        unsigned short* tb = triT + b * TRIN + ttb;
        tb[0]  = f2bf(vX);
        tb[32] = f2bf(vY);
    }
}

// ---------------- K4: fused sample + 3-layer MLP + heads (R9-good structure) ----------------
template<int K, bool INPLACE>
__device__ __forceinline__ void mlp_layer(
    const unsigned char* bin, unsigned char* bout, int LDIN,
    const unsigned short* __restrict__ wtp, const float* __restrict__ mb,
    int lane, int c4)
{
    const int l15 = lane & 15;
    const int kg = lane >> 4;
    const int n0 = c4 * 64;
    f32x4 acc[4][4];
    #pragma unroll
    for (int rf = 0; rf < 4; ++rf)
        #pragma unroll
        for (int cf = 0; cf < 4; ++cf) {
            f32x4 zv = {0.f, 0.f, 0.f, 0.f};
            acc[rf][cf] = zv;
        }
    #pragma unroll
    for (int t = 0; t < K / 32; ++t) {
        uint4 av[4], bv[4];
        #pragma unroll
        for (int rf = 0; rf < 4; ++rf) {
            int row = 16 * rf + l15;
            av[rf] = *(const uint4*)(bin + row * LDIN + ((2 * (t * 32 + kg * 8)) ^ ((row & 7) << 4)));
        }
        #pragma unroll
        for (int cf = 0; cf < 4; ++cf) {
            int n = n0 + 16 * cf + l15;
            bv[cf] = *(const uint4*)(wtp + (((t * 256 + n) * 4 + kg) << 3));
        }
        __builtin_amdgcn_s_setprio(1);
        #pragma unroll
        for (int rf = 0; rf < 4; ++rf)
            #pragma unroll
            for (int cf = 0; cf < 4; ++cf)
                acc[rf][cf] = __builtin_amdgcn_mfma_f32_16x16x32_bf16(
                    __builtin_bit_cast(bf16x8, av[rf]),
                    __builtin_bit_cast(bf16x8, bv[cf]),
                    acc[rf][cf], 0, 0, 0);
        __builtin_amdgcn_s_setprio(0);
    }
    if (INPLACE) __syncthreads();            // all reads of bin done before overwrite
    float bias[4];
    #pragma unroll
    for (int cf = 0; cf < 4; ++cf) bias[cf] = mb[n0 + 16 * cf + l15];
    const int pbyte = (n0 + l15 * 4) * 2;    // sigma stored position (bytes)
    #pragma unroll
    for (int rf = 0; rf < 4; ++rf) {
        #pragma unroll
        for (int jj = 0; jj < 4; ++jj) {
            int row = 16 * rf + kg * 4 + jj;
            float v0 = silu_f(acc[rf][0][jj] + bias[0]);
            float v1 = silu_f(acc[rf][1][jj] + bias[1]);
            float v2 = silu_f(acc[rf][2][jj] + bias[2]);
            float v3 = silu_f(acc[rf][3][jj] + bias[3]);
            uint2 pk;
            pk.x = cvt_pk_bf16(v0, v1);
            pk.y = cvt_pk_bf16(v2, v3);
            *(uint2*)(bout + row * 512 + (pbyte ^ ((row & 7) << 4))) = pk;
        }
    }
    __syncthreads();
}

// DIAGNOSTIC: grid x4, bid = blockIdx.x & 4095 -> blocks 4096+ exactly mirror
// 0..4095 (idempotent, bit-identical output). No codegen change inside the
// block -> counters (VGPR/MfmaUtil/VALUBusy/FETCH/conflicts) are the TRUE ones,
// and the ~600us dispatch surfaces above the harness fill kernels.
__global__ __launch_bounds__(256) void k_mlp(
    const float* __restrict__ qp, const unsigned short* __restrict__ triT,
    const unsigned short* __restrict__ wt0, const unsigned short* __restrict__ wt1,
    const unsigned short* __restrict__ wt2,
    const float* __restrict__ mb0, const float* __restrict__ mb1, const float* __restrict__ mb2,
    const float* __restrict__ sdfp, const float* __restrict__ sdf_b,
    const float* __restrict__ occp, const float* __restrict__ occ_b,
    float* __restrict__ out)
{
    __shared__ __align__(16) unsigned char lds[49152];
    unsigned char* x0  = lds;            // 16 KB: X0, 64 rows x 256 B
    unsigned char* act = lds + 16384;    // 32 KB: act, 64 rows x 512 B
    unsigned char* scr = act;            // 192*32 B coord scratch (dead after phase B)
    const int t = threadIdx.x;

    const int bid = blockIdx.x & 4095;   // DIAGNOSTIC mirror
    const int xcd = bid & 7;
    const int batch = xcd >> 1;
    const int brow = (bid >> 3) + ((xcd & 1) << 9);   // 0..1023
    const int row0 = batch * QPB + brow * 64;

    // ---- phase A: per (q,plane) corner BYTE offsets + weights -> scr ----
    if (t < 192) {
        int plane = t >> 6, q = t & 63;
        int gr = row0 + q;
        float px = qp[3 * gr], py = qp[3 * gr + 1], pz = qp[3 * gr + 2];
        float u = (plane == 2) ? py : px;
        float v = (plane == 0) ? py : pz;
        u = fminf(fmaxf(u, -1.f), 1.f);
        v = fminf(fmaxf(v, -1.f), 1.f);
        float xf = (u + 1.f) * 31.5f;
        float yf = (v + 1.f) * 31.5f;
        float x0f = floorf(xf), y0f = floorf(yf);
        float wx = xf - x0f, wy = yf - y0f;
        int xi = min(max((int)x0f, 0), 63);
        int yi = min(max((int)y0f, 0), 63);
        int xi1 = min(xi + 1, 63), yi1 = min(yi + 1, 63);
        int pb = (batch * 3 + plane) * 64;
        int4 offs;                             // byte offsets (64 B bf16 rows)
        offs.x = ((pb + yi ) * 64 + xi ) << 6;
        offs.y = ((pb + yi ) * 64 + xi1) << 6;
        offs.z = ((pb + yi1) * 64 + xi ) << 6;
        offs.w = ((pb + yi1) * 64 + xi1) << 6;
        float4 w;
        w.x = (1.f - wx) * (1.f - wy); w.y = wx * (1.f - wy);
        w.z = (1.f - wx) * wy;         w.w = wx * wy;
        *(int4*)(scr + t * 32) = offs;
        *(float4*)(scr + t * 32 + 16) = w;
        if (plane == 0) {
            int swz = (q & 7) << 4;
            uint4 c0;
            c0.x = (unsigned)f2bf(px) | ((unsigned)f2bf(py) << 16);
            c0.y = (unsigned)f2bf(pz);
            c0.z = 0u; c0.w = 0u;
            uint4 z4; z4.x = z4.y = z4.z = z4.w = 0u;
            *(uint4*)(x0 + q * 256 + ((192) ^ swz)) = c0;
            *(uint4*)(x0 + q * 256 + ((208) ^ swz)) = z4;
            *(uint4*)(x0 + q * 256 + ((224) ^ swz)) = z4;
            *(uint4*)(x0 + q * 256 + ((240) ^ swz)) = z4;
        }
    }
    __syncthreads();

    // ---- phase B: gather+blend from bf16 triT; 768 units = 192 x 4 chunks ----
    const char* tb8 = (const char*)triT;
    #pragma unroll
    for (int i = 0; i < 3; ++i) {
        int unit = i * 256 + t;
        int chunk = unit & 3;
        int uc = unit >> 2;                  // = plane*64 + q
        const unsigned char* ce = scr + uc * 32;
        int4 offs = *(const int4*)ce;
        float4 w = *(const float4*)(ce + 16);
        int cb = chunk * 16;
        uint4 c0 = *(const uint4*)(tb8 + offs.x + cb);
        uint4 c1 = *(const uint4*)(tb8 + offs.y + cb);
        uint4 c2 = *(const uint4*)(tb8 + offs.z + cb);
        uint4 c3 = *(const uint4*)(tb8 + offs.w + cb);
        const unsigned* u0 = (const unsigned*)&c0;
        const unsigned* u1 = (const unsigned*)&c1;
        const unsigned* u2 = (const unsigned*)&c2;
        const unsigned* u3 = (const unsigned*)&c3;
        unsigned r[4];
        #pragma unroll
        for (int q2 = 0; q2 < 4; ++q2) {
            float lo = w.x * bflo(u0[q2]) + w.y * bflo(u1[q2])
                     + w.z * bflo(u2[q2]) + w.w * bflo(u3[q2]);
            float hi = w.x * bfhi(u0[q2]) + w.y * bfhi(u1[q2])
                     + w.z * bfhi(u2[q2]) + w.w * bfhi(u3[q2]);
            r[q2] = cvt_pk_bf16(lo, hi);
        }
        int q = uc & 63, plane = uc >> 6;
        int colb = plane * 64 + chunk * 16;
        uint4 pk; pk.x = r[0]; pk.y = r[1]; pk.z = r[2]; pk.w = r[3];
        *(uint4*)(x0 + q * 256 + (colb ^ ((q & 7) << 4))) = pk;
    }
    __syncthreads();

    const int lane = t & 63;
    const int c4 = t >> 6;                   // col-wave 0..3

    mlp_layer<128, false>(x0,  act, 256, wt0, mb0, lane, c4);
    mlp_layer<256, true >(act, act, 512, wt1, mb1, lane, c4);
    mlp_layer<256, true >(act, act, 512, wt2, mb2, lane, c4);

    // ---- heads: sdf / occ (act holds sigma-permuted cols; weights pre-permuted) ----
    {
        const int l15 = lane & 15;
        const int kg = lane >> 4;
        int row = c4 * 16 + l15;             // 0..63
        int gr = row0 + row;
        float aS = 0.f, aO = 0.f;
        int kb = kg * 64;
        #pragma unroll
        for (int i = 0; i < 8; ++i) {
            int k = kb + i * 8;
            uint4 xv = *(const uint4*)(act + row * 512 + ((k * 2) ^ ((row & 7) << 4)));
            const unsigned* xu = (const unsigned*)&xv;
            float4 s0 = *(const float4*)(sdfp + k);
            float4 s1 = *(const float4*)(sdfp + k + 4);
            float4 o0 = *(const float4*)(occp + k);
            float4 o1 = *(const float4*)(occp + k + 4);
            float xr[8];
            #pragma unroll
            for (int q = 0; q < 4; ++q) {
                xr[2 * q]     = bflo(xu[q]);
                xr[2 * q + 1] = bfhi(xu[q]);
            }
            aS += xr[0] * s0.x + xr[1] * s0.y + xr[2] * s0.z + xr[3] * s0.w
                + xr[4] * s1.x + xr[5] * s1.y + xr[6] * s1.z + xr[7] * s1.w;
            aO += xr[0] * o0.x + xr[1] * o0.y + xr[2] * o0.z + xr[3] * o0.w
                + xr[4] * o1.x + xr[5] * o1.y + xr[6] * o1.z + xr[7] * o1.w;
        }
        aS += __shfl_xor(aS, 16);
        aS += __shfl_xor(aS, 32);
        aO += __shfl_xor(aO, 16);
        aO += __shfl_xor(aO, 32);
        if (kg == 0) {
            out[TRI_OUT + gr] = aS + sdf_b[0];
            out[TRI_OUT + QTOT + gr] = aO + occ_b[0];
        }
    }
}

extern "C" void kernel_launch(void* const* d_in, const int* in_sizes, int n_in,
                              void* d_out, int out_size, void* d_ws, size_t ws_size,
                              hipStream_t stream)
{
    const float* z     = (const float*)d_in[0];
    const float* qp    = (const float*)d_in[1];
    const float* w1    = (const float*)d_in[2];
    const float* b1    = (const float*)d_in[3];
    const float* w2    = (const float*)d_in[4];
    const float* b2    = (const float*)d_in[5];
    const float* mw0   = (const float*)d_in[6];
    const float* mb0   = (const float*)d_in[7];
    const float* mw1   = (const float*)d_in[8];
    const float* mb1   = (const float*)d_in[9];
    const float* mw2   = (const float*)d_in[10];
    const float* mb2   = (const float*)d_in[11];
    const float* sdf_w = (const float*)d_in[12];
    const float* sdf_b = (const float*)d_in[13];
    const float* occ_w = (const float*)d_in[14];
    const float* occ_b = (const float*)d_in[15];
    float* out = (float*)d_out;
    char* ws = (char*)d_ws;

    float* h_ws          = (float*)(ws);                    // 8192 B
    unsigned short* wt0  = (unsigned short*)(ws + 8192);    // 65536 B
    unsigned short* wt1  = (unsigned short*)(ws + 73728);   // 131072 B
    unsigned short* wt2  = (unsigned short*)(ws + 204800);  // 131072 B
    float* sdfp          = (float*)(ws + 335872);           // 1024 B
    float* occp          = (float*)(ws + 336896);           // 1024 B
    unsigned short* triT = (unsigned short*)(ws + 337920);  // 3145728 B (bf16)

    k_prep_w<<<643, 256, 0, stream>>>(mw0, mw1, mw2, sdf_w, occ_w,
                                      wt0, wt1, wt2, sdfp, occp);
    k_h<<<8, 256, 0, stream>>>(z, w1, b1, h_ws);
    k_triplane<<<768, 256, 0, stream>>>(w2, b2, h_ws, out, triT);
    // DIAGNOSTIC: grid x4 (16384 blocks), mirrored via bid & 4095.
    k_mlp<<<16384, 256, 0, stream>>>(qp, triT, wt0, wt1, wt2,
                                     mb0, mb1, mb2, sdfp, sdf_b, occp, occ_b, out);
}

// Round 12
// 385.582 us; speedup vs baseline: 1.7467x; 1.7467x over previous
//
#include <hip/hip_runtime.h>
#include <cstdint>

#define BQ 4
#define QPB 65536
#define QTOT (BQ*QPB)          /* 262144 */
#define TRIN 393216            /* 3*32*64*64 */
#define TRI_OUT (BQ*TRIN)      /* 1572864 */

typedef __attribute__((ext_vector_type(8))) __bf16 bf16x8;
typedef __attribute__((ext_vector_type(4))) float f32x4;

__device__ __forceinline__ unsigned short f2bf(float f) {
    unsigned u = __float_as_uint(f);
    u += 0x7fffu + ((u >> 16) & 1u);
    return (unsigned short)(u >> 16);
}
__device__ __forceinline__ float bflo(unsigned u) {
    return __uint_as_float(u << 16);
}
__device__ __forceinline__ float bfhi(unsigned u) {
    return __uint_as_float(u & 0xffff0000u);
}
__device__ __forceinline__ unsigned cvt_pk_bf16(float lo, float hi) {
    unsigned r;
    asm("v_cvt_pk_bf16_f32 %0, %1, %2" : "=v"(r) : "v"(lo), "v"(hi));
    return r;
}
__device__ __forceinline__ float fast_rcp(float d) {
    float r;
    asm("v_rcp_f32 %0, %1" : "=v"(r) : "v"(d));
    return r;
}
__device__ __forceinline__ float silu_f(float x) {
    return x * fast_rcp(1.0f + __expf(-x));
}
// stored position within a 64-col group -> true column (sigma^-1)
__device__ __forceinline__ int c_true(int p) {
    return (p & ~63) + ((p & 3) * 16 + ((p & 63) >> 2));
}

// ---------------- K0: pack MLP weights (fragment order + sigma K-permute) ----------------
__global__ __launch_bounds__(256) void k_prep_w(
    const float* __restrict__ mw0, const float* __restrict__ mw1, const float* __restrict__ mw2,
    const float* __restrict__ sdf_w, const float* __restrict__ occ_w,
    unsigned short* __restrict__ wt0, unsigned short* __restrict__ wt1,
    unsigned short* __restrict__ wt2, float* __restrict__ sdfp, float* __restrict__ occp)
{
    int idx = blockIdx.x * 256 + threadIdx.x;
    if (idx < 163840) {
        const float* src;
        unsigned short* dst;
        int rel;
        bool perm;
        int kmax;
        if (idx < 32768)       { rel = idx;         src = mw0; dst = wt0; perm = false; kmax = 99;  }
        else if (idx < 98304)  { rel = idx - 32768; src = mw1; dst = wt1; perm = true;  kmax = 256; }
        else                   { rel = idx - 98304; src = mw2; dst = wt2; perm = true;  kmax = 256; }
        int e  = rel & 7;
        int kg = (rel >> 3) & 3;
        int n  = (rel >> 5) & 255;
        int t  = rel >> 13;
        int ks = t * 32 + kg * 8 + e;          // stored k
        int k  = perm ? c_true(ks) : ks;       // source k
        float v = (ks < kmax) ? src[k * 256 + n] : 0.0f;
        dst[rel] = f2bf(v);
    } else if (idx < 164352) {
        int r = idx - 163840;
        int p = r & 255, which = r >> 8;
        float v = (which ? occ_w : sdf_w)[c_true(p)];
        (which ? occp : sdfp)[p] = v;
    }
}

// ---------------- K1: h = silu(z @ w1 + b1), [4][512] f32 ----------------
__global__ __launch_bounds__(256) void k_h(
    const float* __restrict__ z, const float* __restrict__ w1,
    const float* __restrict__ b1, float* __restrict__ hout)
{
    int gid = blockIdx.x * 256 + threadIdx.x;   // 2048 total
    int b = gid >> 9, n = gid & 511;
    float acc = b1[n];
    #pragma unroll 8
    for (int k = 0; k < 256; ++k)
        acc += z[b * 256 + k] * w1[k * 512 + n];
    hout[gid] = silu_f(acc);
}

// ---------------- K2: triplanes = h @ w2 + b2 (unchanged, near HBM floor) ----------------
__global__ __launch_bounds__(256) void k_triplane(
    const float* __restrict__ w2, const float* __restrict__ b2,
    const float* __restrict__ h, float* __restrict__ outTri,
    unsigned short* __restrict__ triT)
{
    __shared__ float hs[2048];
    int t = threadIdx.x;
    ((float4*)hs)[t]       = ((const float4*)h)[t];
    ((float4*)hs)[t + 256] = ((const float4*)h)[t + 256];
    __syncthreads();
    int g = blockIdx.x * 256 + t;            // 196608 threads
    int j = g * 2;
    const float* wj = w2 + j;
    float ax[4] = {0.f, 0.f, 0.f, 0.f}, ay[4] = {0.f, 0.f, 0.f, 0.f};

    for (int k0 = 0; k0 < 512; k0 += 8) {
        float2 wv[8];
        #pragma unroll
        for (int u = 0; u < 8; ++u)
            wv[u] = *(const float2*)(wj + (size_t)(k0 + u) * TRIN);
        float4 hv[4][2];
        #pragma unroll
        for (int b = 0; b < 4; ++b) {
            hv[b][0] = *(const float4*)&hs[b * 512 + k0];
            hv[b][1] = *(const float4*)&hs[b * 512 + k0 + 4];
        }
        #pragma unroll
        for (int b = 0; b < 4; ++b) {
            ax[b] += hv[b][0].x * wv[0].x + hv[b][0].y * wv[1].x
                   + hv[b][0].z * wv[2].x + hv[b][0].w * wv[3].x
                   + hv[b][1].x * wv[4].x + hv[b][1].y * wv[5].x
                   + hv[b][1].z * wv[6].x + hv[b][1].w * wv[7].x;
            ay[b] += hv[b][0].x * wv[0].y + hv[b][0].y * wv[1].y
                   + hv[b][0].z * wv[2].y + hv[b][0].w * wv[3].y
                   + hv[b][1].x * wv[4].y + hv[b][1].y * wv[5].y
                   + hv[b][1].z * wv[6].y + hv[b][1].w * wv[7].y;
        }
    }

    float2 bj = *(const float2*)(b2 + j);
    int x = j & 63, y = (j >> 6) & 63, c = (j >> 12) & 31, p = j >> 17;
    int ttb = ((p * 64 + y) * 64 + x) * 32 + c;
    #pragma unroll
    for (int b = 0; b < 4; ++b) {
        float vX = ax[b] + bj.x, vY = ay[b] + bj.y;
        float2 o; o.x = vX; o.y = vY;
        *(float2*)(outTri + (size_t)b * TRIN + j) = o;
        unsigned short* tb = triT + b * TRIN + ttb;
        tb[0]  = f2bf(vX);
        tb[32] = f2bf(vY);
    }
}

// ---------------- K4: fused sample + 3-layer MLP + heads ----------------
// 32 rows/block, 256 thr (4 col-waves x 64 cols), 24 KB LDS -> 6 blocks/CU.
template<int K, bool INPLACE>
__device__ __forceinline__ void mlp_layer(
    const unsigned char* bin, unsigned char* bout, int LDIN,
    const unsigned short* __restrict__ wtp, const float* __restrict__ mb,
    int lane, int c4)
{
    const int l15 = lane & 15;
    const int kg = lane >> 4;
    const int n0 = c4 * 64;
    f32x4 acc[2][4];
    #pragma unroll
    for (int rf = 0; rf < 2; ++rf)
        #pragma unroll
        for (int cf = 0; cf < 4; ++cf) {
            f32x4 zv = {0.f, 0.f, 0.f, 0.f};
            acc[rf][cf] = zv;
        }
    #pragma unroll
    for (int t = 0; t < K / 32; ++t) {
        uint4 av[2], bv[4];
        #pragma unroll
        for (int rf = 0; rf < 2; ++rf) {
            int row = 16 * rf + l15;
            av[rf] = *(const uint4*)(bin + row * LDIN + ((2 * (t * 32 + kg * 8)) ^ ((row & 7) << 4)));
        }
        #pragma unroll
        for (int cf = 0; cf < 4; ++cf) {
            int n = n0 + 16 * cf + l15;
            bv[cf] = *(const uint4*)(wtp + (((t * 256 + n) * 4 + kg) << 3));
        }
        __builtin_amdgcn_s_setprio(1);
        #pragma unroll
        for (int rf = 0; rf < 2; ++rf)
            #pragma unroll
            for (int cf = 0; cf < 4; ++cf)
                acc[rf][cf] = __builtin_amdgcn_mfma_f32_16x16x32_bf16(
                    __builtin_bit_cast(bf16x8, av[rf]),
                    __builtin_bit_cast(bf16x8, bv[cf]),
                    acc[rf][cf], 0, 0, 0);
        __builtin_amdgcn_s_setprio(0);
    }
    if (INPLACE) __syncthreads();            // all reads of bin done before overwrite
    float bias[4];
    #pragma unroll
    for (int cf = 0; cf < 4; ++cf) bias[cf] = mb[n0 + 16 * cf + l15];
    const int pbyte = (n0 + l15 * 4) * 2;    // sigma stored position (bytes)
    #pragma unroll
    for (int rf = 0; rf < 2; ++rf) {
        #pragma unroll
        for (int jj = 0; jj < 4; ++jj) {
            int row = 16 * rf + kg * 4 + jj;
            float v0 = silu_f(acc[rf][0][jj] + bias[0]);
            float v1 = silu_f(acc[rf][1][jj] + bias[1]);
            float v2 = silu_f(acc[rf][2][jj] + bias[2]);
            float v3 = silu_f(acc[rf][3][jj] + bias[3]);
            uint2 pk;
            pk.x = cvt_pk_bf16(v0, v1);
            pk.y = cvt_pk_bf16(v2, v3);
            *(uint2*)(bout + row * 512 + (pbyte ^ ((row & 7) << 4))) = pk;
        }
    }
    __syncthreads();
}

__global__ __launch_bounds__(256) void k_mlp(
    const float* __restrict__ qp, const unsigned short* __restrict__ triT,
    const unsigned short* __restrict__ wt0, const unsigned short* __restrict__ wt1,
    const unsigned short* __restrict__ wt2,
    const float* __restrict__ mb0, const float* __restrict__ mb1, const float* __restrict__ mb2,
    const float* __restrict__ sdfp, const float* __restrict__ sdf_b,
    const float* __restrict__ occp, const float* __restrict__ occ_b,
    float* __restrict__ out)
{
    __shared__ __align__(16) unsigned char lds[24576];
    unsigned char* x0  = lds;            //  8 KB: X0, 32 rows x 256 B
    unsigned char* act = lds + 8192;     // 16 KB: act, 32 rows x 512 B
    unsigned char* scr = act;            // 96*32 B coord scratch (dead after phase B)
    const int t = threadIdx.x;

    // batch <-> XCD affinity (bijective: 8192 = 8 XCD * 1024)
    const int bid = blockIdx.x;
    const int xcd = bid & 7;
    const int batch = xcd >> 1;
    const int brow = (bid >> 3) + ((xcd & 1) << 10);  // 0..2047
    const int row0 = batch * QPB + brow * 32;

    // ---- phase A: per (q,plane) corner BYTE offsets + weights -> scr ----
    if (t < 96) {
        int plane = t >> 5, q = t & 31;
        int gr = row0 + q;
        float px = qp[3 * gr], py = qp[3 * gr + 1], pz = qp[3 * gr + 2];
        float u = (plane == 2) ? py : px;
        float v = (plane == 0) ? py : pz;
        u = fminf(fmaxf(u, -1.f), 1.f);
        v = fminf(fmaxf(v, -1.f), 1.f);
        float xf = (u + 1.f) * 31.5f;
        float yf = (v + 1.f) * 31.5f;
        float x0f = floorf(xf), y0f = floorf(yf);
        float wx = xf - x0f, wy = yf - y0f;
        int xi = min(max((int)x0f, 0), 63);
        int yi = min(max((int)y0f, 0), 63);
        int xi1 = min(xi + 1, 63), yi1 = min(yi + 1, 63);
        int pb = (batch * 3 + plane) * 64;
        int4 offs;                             // byte offsets (64 B bf16 rows)
        offs.x = ((pb + yi ) * 64 + xi ) << 6;
        offs.y = ((pb + yi ) * 64 + xi1) << 6;
        offs.z = ((pb + yi1) * 64 + xi ) << 6;
        offs.w = ((pb + yi1) * 64 + xi1) << 6;
        float4 w;
        w.x = (1.f - wx) * (1.f - wy); w.y = wx * (1.f - wy);
        w.z = (1.f - wx) * wy;         w.w = wx * wy;
        *(int4*)(scr + t * 32) = offs;
        *(float4*)(scr + t * 32 + 16) = w;
        if (plane == 0) {
            int swz = (q & 7) << 4;
            uint4 c0;
            c0.x = (unsigned)f2bf(px) | ((unsigned)f2bf(py) << 16);
            c0.y = (unsigned)f2bf(pz);
            c0.z = 0u; c0.w = 0u;
            uint4 z4; z4.x = z4.y = z4.z = z4.w = 0u;
            *(uint4*)(x0 + q * 256 + ((192) ^ swz)) = c0;
            *(uint4*)(x0 + q * 256 + ((208) ^ swz)) = z4;
            *(uint4*)(x0 + q * 256 + ((224) ^ swz)) = z4;
            *(uint4*)(x0 + q * 256 + ((240) ^ swz)) = z4;
        }
    }
    __syncthreads();

    // ---- phase B: gather+blend from bf16 triT; 384 units = 96 x 4 chunks ----
    const char* tb8 = (const char*)triT;
    #pragma unroll
    for (int i = 0; i < 2; ++i) {
        int unit = i * 256 + t;
        if (unit < 384) {
            int chunk = unit & 3;
            int uc = unit >> 2;              // = plane*32 + q
            const unsigned char* ce = scr + uc * 32;
            int4 offs = *(const int4*)ce;
            float4 w = *(const float4*)(ce + 16);
            int cb = chunk * 16;
            uint4 c0 = *(const uint4*)(tb8 + offs.x + cb);
            uint4 c1 = *(const uint4*)(tb8 + offs.y + cb);
            uint4 c2 = *(const uint4*)(tb8 + offs.z + cb);
            uint4 c3 = *(const uint4*)(tb8 + offs.w + cb);
            const unsigned* u0 = (const unsigned*)&c0;
            const unsigned* u1 = (const unsigned*)&c1;
            const unsigned* u2 = (const unsigned*)&c2;
            const unsigned* u3 = (const unsigned*)&c3;
            unsigned r[4];
            #pragma unroll
            for (int q2 = 0; q2 < 4; ++q2) {
                float lo = w.x * bflo(u0[q2]) + w.y * bflo(u1[q2])
                         + w.z * bflo(u2[q2]) + w.w * bflo(u3[q2]);
                float hi = w.x * bfhi(u0[q2]) + w.y * bfhi(u1[q2])
                         + w.z * bfhi(u2[q2]) + w.w * bfhi(u3[q2]);
                r[q2] = cvt_pk_bf16(lo, hi);
            }
            int q = uc & 31, plane = uc >> 5;
            int colb = plane * 64 + chunk * 16;
            uint4 pk; pk.x = r[0]; pk.y = r[1]; pk.z = r[2]; pk.w = r[3];
            *(uint4*)(x0 + q * 256 + (colb ^ ((q & 7) << 4))) = pk;
        }
    }
    __syncthreads();

    const int lane = t & 63;
    const int c4 = t >> 6;                   // col-wave 0..3

    mlp_layer<128, false>(x0,  act, 256, wt0, mb0, lane, c4);
    mlp_layer<256, true >(act, act, 512, wt1, mb1, lane, c4);
    mlp_layer<256, true >(act, act, 512, wt2, mb2, lane, c4);

    // ---- heads: 8 lanes per row; k split into 8 chunks of 32 ----
    {
        int row = t >> 3;                    // 0..31
        int kc = t & 7;
        int gr = row0 + row;
        float aS = 0.f, aO = 0.f;
        #pragma unroll
        for (int i = 0; i < 4; ++i) {
            int k = kc * 32 + i * 8;
            uint4 xv = *(const uint4*)(act + row * 512 + ((k * 2) ^ ((row & 7) << 4)));
            const unsigned* xu = (const unsigned*)&xv;
            float4 s0 = *(const float4*)(sdfp + k);
            float4 s1 = *(const float4*)(sdfp + k + 4);
            float4 o0 = *(const float4*)(occp + k);
            float4 o1 = *(const float4*)(occp + k + 4);
            float xr[8];
            #pragma unroll
            for (int q = 0; q < 4; ++q) {
                xr[2 * q]     = bflo(xu[q]);
                xr[2 * q + 1] = bfhi(xu[q]);
            }
            aS += xr[0] * s0.x + xr[1] * s0.y + xr[2] * s0.z + xr[3] * s0.w
                + xr[4] * s1.x + xr[5] * s1.y + xr[6] * s1.z + xr[7] * s1.w;
            aO += xr[0] * o0.x + xr[1] * o0.y + xr[2] * o0.z + xr[3] * o0.w
                + xr[4] * o1.x + xr[5] * o1.y + xr[6] * o1.z + xr[7] * o1.w;
        }
        aS += __shfl_xor(aS, 1);
        aS += __shfl_xor(aS, 2);
        aS += __shfl_xor(aS, 4);
        aO += __shfl_xor(aO, 1);
        aO += __shfl_xor(aO, 2);
        aO += __shfl_xor(aO, 4);
        if ((t & 7) == 0) {
            out[TRI_OUT + gr] = aS + sdf_b[0];
            out[TRI_OUT + QTOT + gr] = aO + occ_b[0];
        }
    }
}

extern "C" void kernel_launch(void* const* d_in, const int* in_sizes, int n_in,
                              void* d_out, int out_size, void* d_ws, size_t ws_size,
                              hipStream_t stream)
{
    const float* z     = (const float*)d_in[0];
    const float* qp    = (const float*)d_in[1];
    const float* w1    = (const float*)d_in[2];
    const float* b1    = (const float*)d_in[3];
    const float* w2    = (const float*)d_in[4];
    const float* b2    = (const float*)d_in[5];
    const float* mw0   = (const float*)d_in[6];
    const float* mb0   = (const float*)d_in[7];
    const float* mw1   = (const float*)d_in[8];
    const float* mb1   = (const float*)d_in[9];
    const float* mw2   = (const float*)d_in[10];
    const float* mb2   = (const float*)d_in[11];
    const float* sdf_w = (const float*)d_in[12];
    const float* sdf_b = (const float*)d_in[13];
    const float* occ_w = (const float*)d_in[14];
    const float* occ_b = (const float*)d_in[15];
    float* out = (float*)d_out;
    char* ws = (char*)d_ws;

    float* h_ws          = (float*)(ws);                    // 8192 B
    unsigned short* wt0  = (unsigned short*)(ws + 8192);    // 65536 B
    unsigned short* wt1  = (unsigned short*)(ws + 73728);   // 131072 B
    unsigned short* wt2  = (unsigned short*)(ws + 204800);  // 131072 B
    float* sdfp          = (float*)(ws + 335872);           // 1024 B
    float* occp          = (float*)(ws + 336896);           // 1024 B
    unsigned short* triT = (unsigned short*)(ws + 337920);  // 3145728 B (bf16)

    k_prep_w<<<643, 256, 0, stream>>>(mw0, mw1, mw2, sdf_w, occ_w,
                                      wt0, wt1, wt2, sdfp, occp);
    k_h<<<8, 256, 0, stream>>>(z, w1, b1, h_ws);
    k_triplane<<<768, 256, 0, stream>>>(w2, b2, h_ws, out, triT);
    k_mlp<<<8192, 256, 0, stream>>>(qp, triT, wt0, wt1, wt2,
                                    mb0, mb1, mb2, sdfp, sdf_b, occp, occ_b, out);
}

// Round 13
// 304.836 us; speedup vs baseline: 2.2093x; 1.2649x over previous
//
#include <hip/hip_runtime.h>
#include <cstdint>

#define BQ 4
#define QPB 65536
#define QTOT (BQ*QPB)          /* 262144 */
#define TRIN 393216            /* 3*32*64*64 */
#define TRI_OUT (BQ*TRIN)      /* 1572864 */

#define X0LD 272               /* padded x0 row stride (bytes) */
#define ACTLD 528              /* padded act row stride (bytes) */

typedef __attribute__((ext_vector_type(8))) __bf16 bf16x8;
typedef __attribute__((ext_vector_type(4))) float f32x4;

__device__ __forceinline__ unsigned short f2bf(float f) {
    unsigned u = __float_as_uint(f);
    u += 0x7fffu + ((u >> 16) & 1u);
    return (unsigned short)(u >> 16);
}
__device__ __forceinline__ float bflo(unsigned u) {
    return __uint_as_float(u << 16);
}
__device__ __forceinline__ float bfhi(unsigned u) {
    return __uint_as_float(u & 0xffff0000u);
}
__device__ __forceinline__ unsigned cvt_pk_bf16(float lo, float hi) {
    unsigned r;
    asm("v_cvt_pk_bf16_f32 %0, %1, %2" : "=v"(r) : "v"(lo), "v"(hi));
    return r;
}
__device__ __forceinline__ float fast_rcp(float d) {
    float r;
    asm("v_rcp_f32 %0, %1" : "=v"(r) : "v"(d));
    return r;
}
__device__ __forceinline__ float silu_f(float x) {
    return x * fast_rcp(1.0f + __expf(-x));
}
// stored position within a 64-col group -> true column (sigma^-1)
__device__ __forceinline__ int c_true(int p) {
    return (p & ~63) + ((p & 3) * 16 + ((p & 63) >> 2));
}

// ---------------- K0: pack MLP weights (fragment order + sigma K-permute) ----------------
__global__ __launch_bounds__(256) void k_prep_w(
    const float* __restrict__ mw0, const float* __restrict__ mw1, const float* __restrict__ mw2,
    const float* __restrict__ sdf_w, const float* __restrict__ occ_w,
    unsigned short* __restrict__ wt0, unsigned short* __restrict__ wt1,
    unsigned short* __restrict__ wt2, float* __restrict__ sdfp, float* __restrict__ occp)
{
    int idx = blockIdx.x * 256 + threadIdx.x;
    if (idx < 163840) {
        const float* src;
        unsigned short* dst;
        int rel;
        bool perm;
        int kmax;
        if (idx < 32768)       { rel = idx;         src = mw0; dst = wt0; perm = false; kmax = 99;  }
        else if (idx < 98304)  { rel = idx - 32768; src = mw1; dst = wt1; perm = true;  kmax = 256; }
        else                   { rel = idx - 98304; src = mw2; dst = wt2; perm = true;  kmax = 256; }
        int e  = rel & 7;
        int kg = (rel >> 3) & 3;
        int n  = (rel >> 5) & 255;
        int t  = rel >> 13;
        int ks = t * 32 + kg * 8 + e;          // stored k
        int k  = perm ? c_true(ks) : ks;       // source k
        float v = (ks < kmax) ? src[k * 256 + n] : 0.0f;
        dst[rel] = f2bf(v);
    } else if (idx < 164352) {
        int r = idx - 163840;
        int p = r & 255, which = r >> 8;
        float v = (which ? occ_w : sdf_w)[c_true(p)];
        (which ? occp : sdfp)[p] = v;
    }
}

// ---------------- K1: h = silu(z @ w1 + b1), [4][512] f32 ----------------
__global__ __launch_bounds__(256) void k_h(
    const float* __restrict__ z, const float* __restrict__ w1,
    const float* __restrict__ b1, float* __restrict__ hout)
{
    int gid = blockIdx.x * 256 + threadIdx.x;   // 2048 total
    int b = gid >> 9, n = gid & 511;
    float acc = b1[n];
    #pragma unroll 8
    for (int k = 0; k < 256; ++k)
        acc += z[b * 256 + k] * w1[k * 512 + n];
    hout[gid] = silu_f(acc);
}

// ---------------- K2: triplanes = h @ w2 + b2 (unchanged, near HBM floor) ----------------
__global__ __launch_bounds__(256) void k_triplane(
    const float* __restrict__ w2, const float* __restrict__ b2,
    const float* __restrict__ h, float* __restrict__ outTri,
    unsigned short* __restrict__ triT)
{
    __shared__ float hs[2048];
    int t = threadIdx.x;
    ((float4*)hs)[t]       = ((const float4*)h)[t];
    ((float4*)hs)[t + 256] = ((const float4*)h)[t + 256];
    __syncthreads();
    int g = blockIdx.x * 256 + t;            // 196608 threads
    int j = g * 2;
    const float* wj = w2 + j;
    float ax[4] = {0.f, 0.f, 0.f, 0.f}, ay[4] = {0.f, 0.f, 0.f, 0.f};

    for (int k0 = 0; k0 < 512; k0 += 8) {
        float2 wv[8];
        #pragma unroll
        for (int u = 0; u < 8; ++u)
            wv[u] = *(const float2*)(wj + (size_t)(k0 + u) * TRIN);
        float4 hv[4][2];
        #pragma unroll
        for (int b = 0; b < 4; ++b) {
            hv[b][0] = *(const float4*)&hs[b * 512 + k0];
            hv[b][1] = *(const float4*)&hs[b * 512 + k0 + 4];
        }
        #pragma unroll
        for (int b = 0; b < 4; ++b) {
            ax[b] += hv[b][0].x * wv[0].x + hv[b][0].y * wv[1].x
                   + hv[b][0].z * wv[2].x + hv[b][0].w * wv[3].x
                   + hv[b][1].x * wv[4].x + hv[b][1].y * wv[5].x
                   + hv[b][1].z * wv[6].x + hv[b][1].w * wv[7].x;
            ay[b] += hv[b][0].x * wv[0].y + hv[b][0].y * wv[1].y
                   + hv[b][0].z * wv[2].y + hv[b][0].w * wv[3].y
                   + hv[b][1].x * wv[4].y + hv[b][1].y * wv[5].y
                   + hv[b][1].z * wv[6].y + hv[b][1].w * wv[7].y;
        }
    }

    float2 bj = *(const float2*)(b2 + j);
    int x = j & 63, y = (j >> 6) & 63, c = (j >> 12) & 31, p = j >> 17;
    int ttb = ((p * 64 + y) * 64 + x) * 32 + c;
    #pragma unroll
    for (int b = 0; b < 4; ++b) {
        float vX = ax[b] + bj.x, vY = ay[b] + bj.y;
        float2 o; o.x = vX; o.y = vY;
        *(float2*)(outTri + (size_t)b * TRIN + j) = o;
        unsigned short* tb = triT + b * TRIN + ttb;
        tb[0]  = f2bf(vX);
        tb[32] = f2bf(vY);
    }
}

// ---------------- K4: fused sample + 3-layer MLP + heads ----------------
// R9 geometry (64 rows/block, 256 thr, 3 blocks/CU), but PADDED row strides
// instead of XOR swizzle: x0 rows 272 B, act rows 528 B. Stride 272/528 B is
// 4 dword-banks mod 32 -> column reads are 2-way bank aliased (free, m136);
// every address is affine in compile-time indices -> base + immediate offsets.
template<int K, bool INPLACE, int LDIN>
__device__ __forceinline__ void mlp_layer(
    const unsigned char* bin, unsigned char* bout,
    const unsigned short* __restrict__ wtp, const float* __restrict__ mb,
    int lane, int c4)
{
    const int l15 = lane & 15;
    const int kg = lane >> 4;
    const int n0 = c4 * 64;
    const unsigned char* abase = bin + l15 * LDIN + kg * 16;   // + rf*16*LDIN + 64t (imm)
    f32x4 acc[4][4];
    #pragma unroll
    for (int rf = 0; rf < 4; ++rf)
        #pragma unroll
        for (int cf = 0; cf < 4; ++cf) {
            f32x4 zv = {0.f, 0.f, 0.f, 0.f};
            acc[rf][cf] = zv;
        }
    #pragma unroll
    for (int t = 0; t < K / 32; ++t) {
        uint4 av[4], bv[4];
        #pragma unroll
        for (int rf = 0; rf < 4; ++rf)
            av[rf] = *(const uint4*)(abase + rf * 16 * LDIN + t * 64);
        #pragma unroll
        for (int cf = 0; cf < 4; ++cf) {
            int n = n0 + 16 * cf + l15;
            bv[cf] = *(const uint4*)(wtp + (((t * 256 + n) * 4 + kg) << 3));
        }
        __builtin_amdgcn_s_setprio(1);
        #pragma unroll
        for (int rf = 0; rf < 4; ++rf)
            #pragma unroll
            for (int cf = 0; cf < 4; ++cf)
                acc[rf][cf] = __builtin_amdgcn_mfma_f32_16x16x32_bf16(
                    __builtin_bit_cast(bf16x8, av[rf]),
                    __builtin_bit_cast(bf16x8, bv[cf]),
                    acc[rf][cf], 0, 0, 0);
        __builtin_amdgcn_s_setprio(0);
    }
    if (INPLACE) __syncthreads();            // all reads of bin done before overwrite
    float bias[4];
    #pragma unroll
    for (int cf = 0; cf < 4; ++cf) bias[cf] = mb[n0 + 16 * cf + l15];
    // sigma store: positions n0 + l15*4 + {0..3}; base affine per thread.
    unsigned char* sbase = bout + kg * 4 * ACTLD + (n0 + l15 * 4) * 2;
    #pragma unroll
    for (int rf = 0; rf < 4; ++rf) {
        #pragma unroll
        for (int jj = 0; jj < 4; ++jj) {
            float v0 = silu_f(acc[rf][0][jj] + bias[0]);
            float v1 = silu_f(acc[rf][1][jj] + bias[1]);
            float v2 = silu_f(acc[rf][2][jj] + bias[2]);
            float v3 = silu_f(acc[rf][3][jj] + bias[3]);
            uint2 pk;
            pk.x = cvt_pk_bf16(v0, v1);
            pk.y = cvt_pk_bf16(v2, v3);
            *(uint2*)(sbase + (rf * 16 + jj) * ACTLD) = pk;
        }
    }
    __syncthreads();
}

__global__ __launch_bounds__(256) void k_mlp(
    const float* __restrict__ qp, const unsigned short* __restrict__ triT,
    const unsigned short* __restrict__ wt0, const unsigned short* __restrict__ wt1,
    const unsigned short* __restrict__ wt2,
    const float* __restrict__ mb0, const float* __restrict__ mb1, const float* __restrict__ mb2,
    const float* __restrict__ sdfp, const float* __restrict__ sdf_b,
    const float* __restrict__ occp, const float* __restrict__ occ_b,
    float* __restrict__ out)
{
    __shared__ __align__(16) unsigned char lds[64 * X0LD + 64 * ACTLD];  // 51200 B
    unsigned char* x0  = lds;                  // 64 rows x 272 B
    unsigned char* act = lds + 64 * X0LD;      // 64 rows x 528 B
    unsigned char* scr = act;                  // 192*32 B coord scratch (dead after phase B)
    const int t = threadIdx.x;

    // batch <-> XCD affinity (bijective: 4096 = 8 XCD * 512)
    const int bid = blockIdx.x;
    const int xcd = bid & 7;
    const int batch = xcd >> 1;
    const int brow = (bid >> 3) + ((xcd & 1) << 9);   // 0..1023
    const int row0 = batch * QPB + brow * 64;

    // ---- phase A: per (q,plane) corner BYTE offsets + weights -> scr ----
    if (t < 192) {
        int plane = t >> 6, q = t & 63;
        int gr = row0 + q;
        float px = qp[3 * gr], py = qp[3 * gr + 1], pz = qp[3 * gr + 2];
        float u = (plane == 2) ? py : px;
        float v = (plane == 0) ? py : pz;
        u = fminf(fmaxf(u, -1.f), 1.f);
        v = fminf(fmaxf(v, -1.f), 1.f);
        float xf = (u + 1.f) * 31.5f;
        float yf = (v + 1.f) * 31.5f;
        float x0f = floorf(xf), y0f = floorf(yf);
        float wx = xf - x0f, wy = yf - y0f;
        int xi = min(max((int)x0f, 0), 63);
        int yi = min(max((int)y0f, 0), 63);
        int xi1 = min(xi + 1, 63), yi1 = min(yi + 1, 63);
        int pb = (batch * 3 + plane) * 64;
        int4 offs;                             // byte offsets (64 B bf16 rows)
        offs.x = ((pb + yi ) * 64 + xi ) << 6;
        offs.y = ((pb + yi ) * 64 + xi1) << 6;
        offs.z = ((pb + yi1) * 64 + xi ) << 6;
        offs.w = ((pb + yi1) * 64 + xi1) << 6;
        float4 w;
        w.x = (1.f - wx) * (1.f - wy); w.y = wx * (1.f - wy);
        w.z = (1.f - wx) * wy;         w.w = wx * wy;
        *(int4*)(scr + t * 32) = offs;
        *(float4*)(scr + t * 32 + 16) = w;
        if (plane == 0) {
            uint4 c0;
            c0.x = (unsigned)f2bf(px) | ((unsigned)f2bf(py) << 16);
            c0.y = (unsigned)f2bf(pz);
            c0.z = 0u; c0.w = 0u;
            uint4 z4; z4.x = z4.y = z4.z = z4.w = 0u;
            *(uint4*)(x0 + q * X0LD + 192) = c0;
            *(uint4*)(x0 + q * X0LD + 208) = z4;
            *(uint4*)(x0 + q * X0LD + 224) = z4;
            *(uint4*)(x0 + q * X0LD + 240) = z4;
        }
    }
    __syncthreads();

    // ---- phase B: gather+blend from bf16 triT; 768 units = 192 x 4 chunks ----
    const char* tb8 = (const char*)triT;
    #pragma unroll
    for (int i = 0; i < 3; ++i) {
        int unit = i * 256 + t;
        int chunk = unit & 3;
        int uc = unit >> 2;                  // = plane*64 + q
        const unsigned char* ce = scr + uc * 32;
        int4 offs = *(const int4*)ce;
        float4 w = *(const float4*)(ce + 16);
        int cb = chunk * 16;
        uint4 c0 = *(const uint4*)(tb8 + offs.x + cb);
        uint4 c1 = *(const uint4*)(tb8 + offs.y + cb);
        uint4 c2 = *(const uint4*)(tb8 + offs.z + cb);
        uint4 c3 = *(const uint4*)(tb8 + offs.w + cb);
        const unsigned* u0 = (const unsigned*)&c0;
        const unsigned* u1 = (const unsigned*)&c1;
        const unsigned* u2 = (const unsigned*)&c2;
        const unsigned* u3 = (const unsigned*)&c3;
        unsigned r[4];
        #pragma unroll
        for (int q2 = 0; q2 < 4; ++q2) {
            float lo = w.x * bflo(u0[q2]) + w.y * bflo(u1[q2])
                     + w.z * bflo(u2[q2]) + w.w * bflo(u3[q2]);
            float hi = w.x * bfhi(u0[q2]) + w.y * bfhi(u1[q2])
                     + w.z * bfhi(u2[q2]) + w.w * bfhi(u3[q2]);
            r[q2] = cvt_pk_bf16(lo, hi);
        }
        int q = uc & 63, plane = uc >> 6;
        uint4 pk; pk.x = r[0]; pk.y = r[1]; pk.z = r[2]; pk.w = r[3];
        *(uint4*)(x0 + q * X0LD + plane * 64 + chunk * 16) = pk;
    }
    __syncthreads();

    const int lane = t & 63;
    const int c4 = t >> 6;                   // col-wave 0..3

    mlp_layer<128, false, X0LD >(x0,  act, wt0, mb0, lane, c4);
    mlp_layer<256, true,  ACTLD>(act, act, wt1, mb1, lane, c4);
    mlp_layer<256, true,  ACTLD>(act, act, wt2, mb2, lane, c4);

    // ---- heads: sdf / occ (act holds sigma-permuted cols; weights pre-permuted) ----
    {
        const int l15 = lane & 15;
        const int kg = lane >> 4;
        int row = c4 * 16 + l15;             // 0..63
        int gr = row0 + row;
        const unsigned char* hbase = act + row * ACTLD + kg * 128;
        float aS = 0.f, aO = 0.f;
        int kb = kg * 64;
        #pragma unroll
        for (int i = 0; i < 8; ++i) {
            int k = kb + i * 8;
            uint4 xv = *(const uint4*)(hbase + i * 16);
            const unsigned* xu = (const unsigned*)&xv;
            float4 s0 = *(const float4*)(sdfp + k);
            float4 s1 = *(const float4*)(sdfp + k + 4);
            float4 o0 = *(const float4*)(occp + k);
            float4 o1 = *(const float4*)(occp + k + 4);
            float xr[8];
            #pragma unroll
            for (int q = 0; q < 4; ++q) {
                xr[2 * q]     = bflo(xu[q]);
                xr[2 * q + 1] = bfhi(xu[q]);
            }
            aS += xr[0] * s0.x + xr[1] * s0.y + xr[2] * s0.z + xr[3] * s0.w
                + xr[4] * s1.x + xr[5] * s1.y + xr[6] * s1.z + xr[7] * s1.w;
            aO += xr[0] * o0.x + xr[1] * o0.y + xr[2] * o0.z + xr[3] * o0.w
                + xr[4] * o1.x + xr[5] * o1.y + xr[6] * o1.z + xr[7] * o1.w;
        }
        aS += __shfl_xor(aS, 16);
        aS += __shfl_xor(aS, 32);
        aO += __shfl_xor(aO, 16);
        aO += __shfl_xor(aO, 32);
        if (kg == 0) {
            out[TRI_OUT + gr] = aS + sdf_b[0];
            out[TRI_OUT + QTOT + gr] = aO + occ_b[0];
        }
    }
}

extern "C" void kernel_launch(void* const* d_in, const int* in_sizes, int n_in,
                              void* d_out, int out_size, void* d_ws, size_t ws_size,
                              hipStream_t stream)
{
    const float* z     = (const float*)d_in[0];
    const float* qp    = (const float*)d_in[1];
    const float* w1    = (const float*)d_in[2];
    const float* b1    = (const float*)d_in[3];
    const float* w2    = (const float*)d_in[4];
    const float* b2    = (const float*)d_in[5];
    const float* mw0   = (const float*)d_in[6];
    const float* mb0   = (const float*)d_in[7];
    const float* mw1   = (const float*)d_in[8];
    const float* mb1   = (const float*)d_in[9];
    const float* mw2   = (const float*)d_in[10];
    const float* mb2   = (const float*)d_in[11];
    const float* sdf_w = (const float*)d_in[12];
    const float* sdf_b = (const float*)d_in[13];
    const float* occ_w = (const float*)d_in[14];
    const float* occ_b = (const float*)d_in[15];
    float* out = (float*)d_out;
    char* ws = (char*)d_ws;

    float* h_ws          = (float*)(ws);                    // 8192 B
    unsigned short* wt0  = (unsigned short*)(ws + 8192);    // 65536 B
    unsigned short* wt1  = (unsigned short*)(ws + 73728);   // 131072 B
    unsigned short* wt2  = (unsigned short*)(ws + 204800);  // 131072 B
    float* sdfp          = (float*)(ws + 335872);           // 1024 B
    float* occp          = (float*)(ws + 336896);           // 1024 B
    unsigned short* triT = (unsigned short*)(ws + 337920);  // 3145728 B (bf16)

    k_prep_w<<<643, 256, 0, stream>>>(mw0, mw1, mw2, sdf_w, occ_w,
                                      wt0, wt1, wt2, sdfp, occp);
    k_h<<<8, 256, 0, stream>>>(z, w1, b1, h_ws);
    k_triplane<<<768, 256, 0, stream>>>(w2, b2, h_ws, out, triT);
    k_mlp<<<4096, 256, 0, stream>>>(qp, triT, wt0, wt1, wt2,
                                    mb0, mb1, mb2, sdfp, sdf_b, occp, occ_b, out);
}